// Round 3
// baseline (229.328 us; speedup 1.0000x reference)
//
#include <hip/hip_runtime.h>
#include <math.h>

#define B_ 8
#define L_ 1024
#define K_ 1024
#define D_ 128
#define S_ 16
#define DS_ (D_ * S_)

typedef short bf16x8 __attribute__((ext_vector_type(8)));
typedef float f32x4 __attribute__((ext_vector_type(4)));

__device__ inline unsigned short f2bf(float f) {
    unsigned int u = __float_as_uint(f);
    u = (u + 0x7fffu + ((u >> 16) & 1u)) >> 16;   // RNE
    return (unsigned short)u;
}
__device__ inline float bf2f(unsigned short h) {
    return __uint_as_float(((unsigned int)h) << 16);
}

// ---------------------------------------------------------------------------
// Param precompute (double precision): ar/ai = Re/Im(Abar[d,s]), c = delta*Bp*Cp
// Layout [s][d].
// ---------------------------------------------------------------------------
__global__ void k_params(const float* __restrict__ log_Delta,
                         const float* __restrict__ Bp,
                         const float* __restrict__ Cp,
                         const float* __restrict__ log_A_real,
                         const float* __restrict__ A_imag,
                         float* __restrict__ par) {
    int i = blockIdx.x * blockDim.x + threadIdx.x;   // i = d*S + s
    if (i >= DS_) return;
    int d = i >> 4;
    int s = i & 15;
    double delta = exp((double)log_Delta[d]);
    double Are = -exp((double)log_A_real[i]);
    double Aim = (double)A_imag[i];
    double mag = exp(-1e-3 + delta * Are);
    double ang = delta * Aim;
    int o = s * D_ + d;
    par[o]            = (float)(mag * cos(ang));
    par[DS_ + o]      = (float)(mag * sin(ang));
    par[2 * DS_ + o]  = (float)(delta * (double)Bp[i] * (double)Cp[i]);
}

// ---------------------------------------------------------------------------
__global__ __launch_bounds__(256) void k_rownorm(const float* __restrict__ E,
                                                 float* __restrict__ rn) {
    int row = blockIdx.x;
    const float4* p = (const float4*)(E + (size_t)row * K_);
    int t = threadIdx.x;
    float4 v = p[t];
    float s = v.x * v.x + v.y * v.y + v.z * v.z + v.w * v.w;
    #pragma unroll
    for (int off = 32; off > 0; off >>= 1) s += __shfl_down(s, off, 64);
    __shared__ float red[4];
    if ((t & 63) == 0) red[t >> 6] = s;
    __syncthreads();
    if (t == 0) rn[row] = 1.0f / sqrtf(red[0] + red[1] + red[2] + red[3]);
}

// ---------------------------------------------------------------------------
// In-proj: u' = rn[l] * x1 * silu(z)  (rn folded here so GEMM1 uses raw E)
// ---------------------------------------------------------------------------
__global__ __launch_bounds__(256) void k_inproj(
    const float* __restrict__ x, const float* __restrict__ g,
    const float* __restrict__ beta, const float* __restrict__ mean,
    const float* __restrict__ var, const float* __restrict__ W_in,
    const float* __restrict__ b_in, const float* __restrict__ rn,
    float* __restrict__ u) {
    __shared__ float xb[16][128];
    int row0 = blockIdx.x * 16;
    int t = threadIdx.x;
    #pragma unroll
    for (int p = 0; p < 8; ++p) {
        int idx = t + p * 256;
        int dd = idx & 127, r = idx >> 7;
        float sc = g[dd] / sqrtf(var[dd] + 1e-5f);
        xb[r][dd] = (x[(size_t)(row0 + r) * D_ + dd] - mean[dd]) * sc + beta[dd];
    }
    __syncthreads();
    int j = t & 127, half = t >> 7;
    float acc1[8], acc2[8];
    #pragma unroll
    for (int r = 0; r < 8; ++r) { acc1[r] = 0.f; acc2[r] = 0.f; }
    #pragma unroll 4
    for (int dd = 0; dd < 128; ++dd) {
        float w1 = W_in[dd * 256 + j];
        float w2 = W_in[dd * 256 + 128 + j];
        #pragma unroll
        for (int r = 0; r < 8; ++r) {
            float xv = xb[half * 8 + r][dd];
            acc1[r] = fmaf(xv, w1, acc1[r]);
            acc2[r] = fmaf(xv, w2, acc2[r]);
        }
    }
    float b1 = b_in[j], b2 = b_in[128 + j];
    #pragma unroll
    for (int r = 0; r < 8; ++r) {
        int row = row0 + half * 8 + r;
        float x1 = acc1[r] + b1;
        float z  = acc2[r] + b2;
        float sig = 1.0f / (1.0f + __expf(-z));
        u[(size_t)row * D_ + j] = rn[row] * x1 * z * sig;
    }
}

// ---------------------------------------------------------------------------
// Unified MFMA GEMM (split bf16 hi/lo, 3 products -> fp32-level accuracy).
// C[b][m][n] = sum_c A[m][c] * B[c][n],  M=1024, N=128, CC=1024 per batch.
//   TRANSA=1: A[m][c] = Asrc[c][m]   (GEMM1: A = E^T, contraction over l)
//   TRANSA=0: A[m][c] = Asrc[m][c]   (GEMM2: A = E,   contraction over k)
//   B always: B[c][n] = Bsrc[c][n]   (u' or G, [1024][128])
// Tile: 128m x 64n, BK=32. Grid = B*8*2 = 128 blocks, 256 threads (4 waves,
// each 64m x 32n = 4x2 MFMA 16x16x32 tiles). LDS rows stride 40 bf16
// (80 B = 20 dwords; 20*m mod 32 spans all banks -> conflict-free b128).
// ---------------------------------------------------------------------------
template<bool TRANSA>
__global__ __launch_bounds__(256) void k_gemm(
    const float* __restrict__ Asrc, const float* __restrict__ Bsrc,
    float* __restrict__ Cdst) {
    __shared__ unsigned short sA_hi[128 * 40];
    __shared__ unsigned short sA_lo[128 * 40];
    __shared__ unsigned short sB_hi[64 * 40];
    __shared__ unsigned short sB_lo[64 * 40];
    int bx = blockIdx.x;
    int b  = bx >> 4;
    int m0 = ((bx >> 1) & 7) * 128;
    int n0 = (bx & 1) * 64;
    const float* Ab = Asrc + (size_t)b * 1024 * 1024;
    const float* Bb = Bsrc + (size_t)b * 1024 * 128;
    float*       Cb = Cdst + (size_t)b * 1024 * 128;
    int t = threadIdx.x;
    int wave = t >> 6, lane = t & 63;
    int wm = (wave & 1) * 64, wn = (wave >> 1) * 32;
    int fr = lane & 15, q = lane >> 4;
    f32x4 acc[4][2];
    #pragma unroll
    for (int i = 0; i < 4; ++i)
        #pragma unroll
        for (int j = 0; j < 2; ++j) acc[i][j] = (f32x4){0.f, 0.f, 0.f, 0.f};

    for (int c0 = 0; c0 < 1024; c0 += 32) {
        // ---- stage A tile: sA[m 0..127][j 0..31] = A[m0+m][c0+j] ----
        if (TRANSA) {
            // source element = Asrc[c0+j][m0+m]; thread: m = t&127, j = h*16+i
            int m = t & 127, h = t >> 7;
            const float* src = Ab + (size_t)(c0 + h * 16) * 1024 + m0 + m;
            unsigned int hw[8], lw[8];
            #pragma unroll
            for (int i = 0; i < 8; ++i) {
                float v0 = src[(size_t)(2 * i) * 1024];
                float v1 = src[(size_t)(2 * i + 1) * 1024];
                unsigned short h0 = f2bf(v0), h1 = f2bf(v1);
                unsigned short l0 = f2bf(v0 - bf2f(h0));
                unsigned short l1 = f2bf(v1 - bf2f(h1));
                hw[i] = (unsigned int)h0 | ((unsigned int)h1 << 16);
                lw[i] = (unsigned int)l0 | ((unsigned int)l1 << 16);
            }
            uint4* dh = (uint4*)&sA_hi[m * 40 + h * 16];
            uint4* dl = (uint4*)&sA_lo[m * 40 + h * 16];
            dh[0] = (uint4){hw[0], hw[1], hw[2], hw[3]};
            dh[1] = (uint4){hw[4], hw[5], hw[6], hw[7]};
            dl[0] = (uint4){lw[0], lw[1], lw[2], lw[3]};
            dl[1] = (uint4){lw[4], lw[5], lw[6], lw[7]};
        } else {
            #pragma unroll
            for (int r = 0; r < 4; ++r) {
                int idx = t + r * 256;               // [0,1024)
                int m = idx >> 3, j4 = (idx & 7) * 4;
                float4 v = *(const float4*)&Ab[(size_t)(m0 + m) * 1024 + c0 + j4];
                unsigned short h0 = f2bf(v.x), h1 = f2bf(v.y);
                unsigned short h2 = f2bf(v.z), h3 = f2bf(v.w);
                unsigned short l0 = f2bf(v.x - bf2f(h0)), l1 = f2bf(v.y - bf2f(h1));
                unsigned short l2 = f2bf(v.z - bf2f(h2)), l3 = f2bf(v.w - bf2f(h3));
                *(uint2*)&sA_hi[m * 40 + j4] =
                    (uint2){(unsigned int)h0 | ((unsigned int)h1 << 16),
                            (unsigned int)h2 | ((unsigned int)h3 << 16)};
                *(uint2*)&sA_lo[m * 40 + j4] =
                    (uint2){(unsigned int)l0 | ((unsigned int)l1 << 16),
                            (unsigned int)l2 | ((unsigned int)l3 << 16)};
            }
        }
        // ---- stage B tile (transposed): sB[n 0..63][j 0..31] = Bsrc[c0+j][n0+n]
        {
            int n = t & 63, g = t >> 6;              // g in [0,4): j = g*8+i
            const float* src = Bb + (size_t)(c0 + g * 8) * 128 + n0 + n;
            unsigned int hw[4], lw[4];
            #pragma unroll
            for (int i = 0; i < 4; ++i) {
                float v0 = src[(size_t)(2 * i) * 128];
                float v1 = src[(size_t)(2 * i + 1) * 128];
                unsigned short h0 = f2bf(v0), h1 = f2bf(v1);
                unsigned short l0 = f2bf(v0 - bf2f(h0));
                unsigned short l1 = f2bf(v1 - bf2f(h1));
                hw[i] = (unsigned int)h0 | ((unsigned int)h1 << 16);
                lw[i] = (unsigned int)l0 | ((unsigned int)l1 << 16);
            }
            *(uint4*)&sB_hi[n * 40 + g * 8] = (uint4){hw[0], hw[1], hw[2], hw[3]};
            *(uint4*)&sB_lo[n * 40 + g * 8] = (uint4){lw[0], lw[1], lw[2], lw[3]};
        }
        __syncthreads();
        // ---- fragments + MFMA ----
        bf16x8 ahi[4], alo[4], bhi[2], blo[2];
        #pragma unroll
        for (int mt = 0; mt < 4; ++mt) {
            int off = (wm + mt * 16 + fr) * 40 + q * 8;
            ahi[mt] = *(const bf16x8*)&sA_hi[off];
            alo[mt] = *(const bf16x8*)&sA_lo[off];
        }
        #pragma unroll
        for (int nt = 0; nt < 2; ++nt) {
            int off = (wn + nt * 16 + fr) * 40 + q * 8;
            bhi[nt] = *(const bf16x8*)&sB_hi[off];
            blo[nt] = *(const bf16x8*)&sB_lo[off];
        }
        #pragma unroll
        for (int mt = 0; mt < 4; ++mt)
            #pragma unroll
            for (int nt = 0; nt < 2; ++nt) {
                acc[mt][nt] = __builtin_amdgcn_mfma_f32_16x16x32_bf16(
                    ahi[mt], bhi[nt], acc[mt][nt], 0, 0, 0);
                acc[mt][nt] = __builtin_amdgcn_mfma_f32_16x16x32_bf16(
                    ahi[mt], blo[nt], acc[mt][nt], 0, 0, 0);
                acc[mt][nt] = __builtin_amdgcn_mfma_f32_16x16x32_bf16(
                    alo[mt], bhi[nt], acc[mt][nt], 0, 0, 0);
            }
        __syncthreads();
    }
    // ---- store C (C/D layout: col = lane&15, row = quad*4 + reg) ----
    #pragma unroll
    for (int mt = 0; mt < 4; ++mt)
        #pragma unroll
        for (int nt = 0; nt < 2; ++nt) {
            int col = n0 + wn + nt * 16 + fr;
            #pragma unroll
            for (int r = 0; r < 4; ++r) {
                int row = m0 + wm + mt * 16 + q * 4 + r;
                Cb[(size_t)row * 128 + col] = acc[mt][nt][r];
            }
        }
}

// ---------------------------------------------------------------------------
// Complex-ratio epilogue: G[b,k,d] = QTX[b,k,d] * w(ev[b,k], d)
// ---------------------------------------------------------------------------
__global__ __launch_bounds__(256) void k_gepi(
    const float* __restrict__ QTX, const float* __restrict__ EigVals,
    const float* __restrict__ par, float* __restrict__ G) {
    __shared__ float parS[3 * DS_];
    int t = threadIdx.x;
    for (int i = t; i < 3 * DS_; i += 256) parS[i] = par[i];
    __syncthreads();
    int row = blockIdx.x * 8 + (t >> 5);     // b*K + k
    int tx = t & 31;
    int d0 = tx * 4;
    float4 sum = *(const float4*)&QTX[(size_t)row * D_ + d0];
    float ev = 1.0f - EigVals[row];
    float qv[4] = {sum.x, sum.y, sum.z, sum.w};
    float o[4];
    #pragma unroll
    for (int c = 0; c < 4; ++c) {
        int dd = d0 + c;
        float w = 0.f;
        #pragma unroll
        for (int s = 0; s < S_; ++s) {
            float ar = parS[s * D_ + dd];
            float ai = parS[DS_ + s * D_ + dd];
            float cc = parS[2 * DS_ + s * D_ + dd];
            float a = ev * ar, bi = ev * ai;
            float oma = 1.0f - a;            // exact (Sterbenz) for a in [0.5,1]
            float b2 = bi * bi;
            float num = fmaf(a, oma, -b2);
            float den = fmaf(oma, oma, b2);  // no cancellation
            float r = __builtin_amdgcn_rcpf(den);
            r = r * (2.0f - den * r);
            w = fmaf(cc, num * r, w);
        }
        o[c] = qv[c] * w;
    }
    *(float4*)&G[(size_t)row * D_ + d0] = (float4){o[0], o[1], o[2], o[3]};
}

// ---------------------------------------------------------------------------
// yssm*rn -> silu -> out-proj -> y. 16 rows/block, 512 blocks.
// ---------------------------------------------------------------------------
__global__ __launch_bounds__(256) void k_out(
    const float* __restrict__ yssm, const float* __restrict__ rn,
    const float* __restrict__ W_out, const float* __restrict__ b_out,
    float* __restrict__ y) {
    __shared__ float Ys[16][128];
    int row0 = blockIdx.x * 16;              // global row = b*L + l
    int t = threadIdx.x;
    #pragma unroll
    for (int r = 0; r < 2; ++r) {
        int idx = t + r * 256;               // [0,512) float4s
        int rr = idx >> 5, d4 = (idx & 31) * 4;
        int grow = row0 + rr;
        float4 s = *(const float4*)&yssm[(size_t)grow * D_ + d4];
        float rv = rn[grow];
        float o[4] = {s.x * rv, s.y * rv, s.z * rv, s.w * rv};
        #pragma unroll
        for (int c = 0; c < 4; ++c) {
            float sig = 1.0f / (1.0f + __expf(-o[c]));
            Ys[rr][d4 + c] = o[c] * sig;
        }
    }
    __syncthreads();
    int j = t & 127, h = t >> 7;
    float a2[8];
    #pragma unroll
    for (int r = 0; r < 8; ++r) a2[r] = 0.f;
    for (int dd = 0; dd < 128; dd += 4) {
        float w0 = W_out[(dd + 0) * 128 + j];
        float w1 = W_out[(dd + 1) * 128 + j];
        float w2 = W_out[(dd + 2) * 128 + j];
        float w3 = W_out[(dd + 3) * 128 + j];
        #pragma unroll
        for (int r = 0; r < 8; ++r) {
            float4 yv = *(float4*)&Ys[h * 8 + r][dd];
            a2[r] = fmaf(yv.x, w0, a2[r]);
            a2[r] = fmaf(yv.y, w1, a2[r]);
            a2[r] = fmaf(yv.z, w2, a2[r]);
            a2[r] = fmaf(yv.w, w3, a2[r]);
        }
    }
    float bo = b_out[j];
    #pragma unroll
    for (int r = 0; r < 8; ++r)
        y[(size_t)(row0 + h * 8 + r) * D_ + j] = a2[r] + bo;
}

// ---------------------------------------------------------------------------
extern "C" void kernel_launch(void* const* d_in, const int* in_sizes, int n_in,
                              void* d_out, int out_size, void* d_ws, size_t ws_size,
                              hipStream_t stream) {
    const float* x          = (const float*)d_in[0];
    const float* EigVecs    = (const float*)d_in[2];
    const float* EigVals    = (const float*)d_in[3];
    const float* bn_gamma   = (const float*)d_in[4];
    const float* bn_beta    = (const float*)d_in[5];
    const float* bn_mean    = (const float*)d_in[6];
    const float* bn_var     = (const float*)d_in[7];
    const float* W_in       = (const float*)d_in[8];
    const float* b_in       = (const float*)d_in[9];
    const float* log_Delta  = (const float*)d_in[10];
    const float* Bp         = (const float*)d_in[11];
    const float* Cp         = (const float*)d_in[12];
    const float* log_A_real = (const float*)d_in[13];
    const float* A_imag     = (const float*)d_in[14];
    const float* W_out      = (const float*)d_in[15];
    const float* b_out      = (const float*)d_in[16];

    float* y   = (float*)d_out;
    float* ws  = (float*)d_ws;
    float* rn  = ws;                                  // 8192 floats
    float* par = ws + 8192;                           // 6144 floats
    float* QTX = ws + 16384;                          // 1,048,576 floats
    float* G   = ws + 16384 + (size_t)B_ * K_ * D_;   // 1,048,576 floats
    float* yss = QTX;                                 // reuse (QTX dead after gepi)
    float* u   = y;                                   // stage u' in d_out

    k_params<<<dim3(8), dim3(256), 0, stream>>>(log_Delta, Bp, Cp, log_A_real, A_imag, par);
    k_rownorm<<<dim3(B_ * L_), dim3(256), 0, stream>>>(EigVecs, rn);
    k_inproj<<<dim3(B_ * L_ / 16), dim3(256), 0, stream>>>(
        x, bn_gamma, bn_beta, bn_mean, bn_var, W_in, b_in, rn, u);
    // GEMM1: QTX[k][d] = sum_l E[l][k] * u'[l][d]
    k_gemm<true><<<dim3(128), dim3(256), 0, stream>>>(EigVecs, u, QTX);
    k_gepi<<<dim3(B_ * K_ / 8), dim3(256), 0, stream>>>(QTX, EigVals, par, G);
    // GEMM2: yssm[l][d] = sum_k E[l][k] * G[k][d]
    k_gemm<false><<<dim3(128), dim3(256), 0, stream>>>(EigVecs, G, yss);
    k_out<<<dim3(B_ * L_ / 16), dim3(256), 0, stream>>>(yss, rn, W_out, b_out, y);
}

// Round 4
// 184.865 us; speedup vs baseline: 1.2405x; 1.2405x over previous
//
#include <hip/hip_runtime.h>
#include <math.h>

#define B_ 8
#define L_ 1024
#define K_ 1024
#define D_ 128
#define S_ 16
#define DS_ (D_ * S_)
#define KS_ 4            // split-K slices per GEMM
#define CSL_ 256         // contraction slice = 1024/KS_
#define NIT_ 8           // CSL_/32

typedef short bf16x8 __attribute__((ext_vector_type(8)));
typedef float f32x4 __attribute__((ext_vector_type(4)));
typedef __attribute__((address_space(1))) const unsigned int gu32;
typedef __attribute__((address_space(3))) unsigned int lu32;

__device__ inline unsigned short f2bf(float f) {
    unsigned int u = __float_as_uint(f);
    u = (u + 0x7fffu + ((u >> 16) & 1u)) >> 16;   // RNE
    return (unsigned short)u;
}
__device__ inline float bf2f(unsigned short h) {
    return __uint_as_float(((unsigned int)h) << 16);
}

// ---------------------------------------------------------------------------
// Params in double: ar/ai = Re/Im(Abar[d,s]), c = delta*Bp*Cp. Layout [s][d].
// ---------------------------------------------------------------------------
__global__ void k_params(const float* __restrict__ log_Delta,
                         const float* __restrict__ Bp,
                         const float* __restrict__ Cp,
                         const float* __restrict__ log_A_real,
                         const float* __restrict__ A_imag,
                         float* __restrict__ par) {
    int i = blockIdx.x * blockDim.x + threadIdx.x;   // i = d*S + s
    if (i >= DS_) return;
    int d = i >> 4;
    int s = i & 15;
    double delta = exp((double)log_Delta[d]);
    double Are = -exp((double)log_A_real[i]);
    double Aim = (double)A_imag[i];
    double mag = exp(-1e-3 + delta * Are);
    double ang = delta * Aim;
    int o = s * D_ + d;
    par[o]            = (float)(mag * cos(ang));
    par[DS_ + o]      = (float)(mag * sin(ang));
    par[2 * DS_ + o]  = (float)(delta * (double)Bp[i] * (double)Cp[i]);
}

// ---------------------------------------------------------------------------
__global__ __launch_bounds__(256) void k_rownorm(const float* __restrict__ E,
                                                 float* __restrict__ rn) {
    int row = blockIdx.x;
    const float4* p = (const float4*)(E + (size_t)row * K_);
    int t = threadIdx.x;
    float4 v = p[t];
    float s = v.x * v.x + v.y * v.y + v.z * v.z + v.w * v.w;
    #pragma unroll
    for (int off = 32; off > 0; off >>= 1) s += __shfl_down(s, off, 64);
    __shared__ float red[4];
    if ((t & 63) == 0) red[t >> 6] = s;
    __syncthreads();
    if (t == 0) rn[row] = 1.0f / sqrtf(red[0] + red[1] + red[2] + red[3]);
}

// ---------------------------------------------------------------------------
// In-proj: u' = rn * x1 * silu(z), written TRANSPOSED as bf16 hi/lo [b][d][l].
// ---------------------------------------------------------------------------
__global__ __launch_bounds__(256) void k_inproj(
    const float* __restrict__ x, const float* __restrict__ g,
    const float* __restrict__ beta, const float* __restrict__ mean,
    const float* __restrict__ var, const float* __restrict__ W_in,
    const float* __restrict__ b_in, const float* __restrict__ rn,
    unsigned short* __restrict__ uTh, unsigned short* __restrict__ uTl) {
    __shared__ float xb[16][128];
    int row0 = blockIdx.x * 16;
    int t = threadIdx.x;
    #pragma unroll
    for (int p = 0; p < 8; ++p) {
        int idx = t + p * 256;
        int dd = idx & 127, r = idx >> 7;
        float sc = g[dd] / sqrtf(var[dd] + 1e-5f);
        xb[r][dd] = (x[(size_t)(row0 + r) * D_ + dd] - mean[dd]) * sc + beta[dd];
    }
    __syncthreads();
    int j = t & 127, half = t >> 7;
    float acc1[8], acc2[8];
    #pragma unroll
    for (int r = 0; r < 8; ++r) { acc1[r] = 0.f; acc2[r] = 0.f; }
    #pragma unroll 4
    for (int dd = 0; dd < 128; ++dd) {
        float w1 = W_in[dd * 256 + j];
        float w2 = W_in[dd * 256 + 128 + j];
        #pragma unroll
        for (int r = 0; r < 8; ++r) {
            float xv = xb[half * 8 + r][dd];
            acc1[r] = fmaf(xv, w1, acc1[r]);
            acc2[r] = fmaf(xv, w2, acc2[r]);
        }
    }
    float b1 = b_in[j], b2 = b_in[128 + j];
    bf16x8 hv, lv;
    #pragma unroll
    for (int r = 0; r < 8; ++r) {
        int row = row0 + half * 8 + r;
        float x1 = acc1[r] + b1;
        float z  = acc2[r] + b2;
        float sig = 1.0f / (1.0f + __expf(-z));
        float uv = rn[row] * x1 * z * sig;
        unsigned short h = f2bf(uv);
        hv[r] = (short)h;
        lv[r] = (short)f2bf(uv - bf2f(h));
    }
    int b = row0 >> 10;
    int l0 = (row0 & 1023) + half * 8;
    size_t off = ((size_t)b * 128 + j) * 1024 + l0;
    *(bf16x8*)&uTh[off] = hv;
    *(bf16x8*)&uTl[off] = lv;
}

// ---------------------------------------------------------------------------
// MFMA GEMM with split bf16 hi/lo (3 products) and split-K partials.
// C[b][m][n] = sum_c A[m][c]*B[c][n]; M=1024, N=128, contraction 1024.
//   ATRANS=1: A[m][c] = E[b][c][m]  (GEMM1, m=k, c=l)
//   ATRANS=0: A[m][c] = E[b][m][c]  (GEMM2, m=l, c=k)
// B given transposed bf16 hi/lo: Bsrc[b][n][c].
// Block: 128m x 128n, BK=32, c-slice CSL_=256. Grid = 8mt*KS_*B_ = 256.
// 4 waves, each 64x64 (4x4 MFMA 16x16x32, 3 products = 48 MFMA/iter).
// LDS A: [m][40] shorts (pad). LDS B: [q][n][8] packed for global_load_lds.
// ---------------------------------------------------------------------------
template<bool ATRANS>
__global__ __launch_bounds__(256, 1) void k_gemm(
    const float* __restrict__ Asrc,
    const unsigned short* __restrict__ BsrcH,
    const unsigned short* __restrict__ BsrcL,
    float* __restrict__ P) {
    __shared__ unsigned short sAh[2][128 * 40];
    __shared__ unsigned short sAl[2][128 * 40];
    __shared__ unsigned short sBh[2][4096];
    __shared__ unsigned short sBl[2][4096];
    int bx = blockIdx.x;
    int ks = bx & (KS_ - 1);
    int mt8 = (bx >> 2) & 7;
    int b = bx >> 5;
    int m0 = mt8 * 128;
    int cbase = ks * CSL_;
    const float* Ab = Asrc + (size_t)b * 1024 * 1024;
    const unsigned short* BbH = BsrcH + (size_t)b * 128 * 1024;
    const unsigned short* BbL = BsrcL + (size_t)b * 128 * 1024;
    int t = threadIdx.x;
    int wave = t >> 6, lane = t & 63;
    int fr = lane & 15, q = lane >> 4;
    int wm = (wave & 1) * 64, wn = (wave >> 1) * 64;
    f32x4 acc[4][4];
    #pragma unroll
    for (int i = 0; i < 4; ++i)
        #pragma unroll
        for (int j = 0; j < 4; ++j) acc[i][j] = (f32x4){0.f, 0.f, 0.f, 0.f};

    // ---------------- staging helpers (inlined per-iteration) --------------
    // A regs
    float ar16[16];
    // ---- prologue: stage iter 0 into buffer 0 ----
    {
        int cb = cbase;
        if (ATRANS) {
            int m = t & 127, gh = (t >> 7) * 2;
            #pragma unroll
            for (int g2 = 0; g2 < 2; ++g2) {
                int g = gh + g2;
                #pragma unroll
                for (int i = 0; i < 8; ++i)
                    ar16[g2 * 8 + i] = Ab[(size_t)(cb + g * 8 + i) * 1024 + m0 + m];
            }
            #pragma unroll
            for (int g2 = 0; g2 < 2; ++g2) {
                int g = gh + g2;
                bf16x8 hv, lv;
                #pragma unroll
                for (int i = 0; i < 8; ++i) {
                    unsigned short h = f2bf(ar16[g2 * 8 + i]);
                    hv[i] = (short)h;
                    lv[i] = (short)f2bf(ar16[g2 * 8 + i] - bf2f(h));
                }
                *(bf16x8*)&sAh[0][m * 40 + g * 8] = hv;
                *(bf16x8*)&sAl[0][m * 40 + g * 8] = lv;
            }
        } else {
            #pragma unroll
            for (int p = 0; p < 4; ++p) {
                int m = (t >> 3) + p * 32, c4 = (t & 7) * 4;
                float4 v = *(const float4*)&Ab[(size_t)(m0 + m) * 1024 + cb + c4];
                float vv[4] = {v.x, v.y, v.z, v.w};
                unsigned short hs[4], ls[4];
                #pragma unroll
                for (int i = 0; i < 4; ++i) {
                    hs[i] = f2bf(vv[i]);
                    ls[i] = f2bf(vv[i] - bf2f(hs[i]));
                }
                int off = m * 40 + c4;
                *(uint2*)&sAh[0][off] = (uint2){(unsigned)hs[0] | ((unsigned)hs[1] << 16),
                                                (unsigned)hs[2] | ((unsigned)hs[3] << 16)};
                *(uint2*)&sAl[0][off] = (uint2){(unsigned)ls[0] | ((unsigned)ls[1] << 16),
                                                (unsigned)ls[2] | ((unsigned)ls[3] << 16)};
            }
        }
        #pragma unroll
        for (int j = 0; j < 2; ++j) {
            int s = wave * 2 + j;
            int qq = s >> 1, nh = (s & 1) * 64;
            const unsigned short* gh = BbH + (size_t)(nh + lane) * 1024 + cb + qq * 8;
            const unsigned short* gl = BbL + (size_t)(nh + lane) * 1024 + cb + qq * 8;
            __builtin_amdgcn_global_load_lds((gu32*)gh, (lu32*)&sBh[0][qq * 1024 + nh * 8], 16, 0, 0);
            __builtin_amdgcn_global_load_lds((gu32*)gl, (lu32*)&sBl[0][qq * 1024 + nh * 8], 16, 0, 0);
        }
    }
    __syncthreads();

    for (int it = 0; it < NIT_; ++it) {
        int cur = it & 1, nxt = cur ^ 1;
        int cb = cbase + (it + 1) * 32;
        bool pre = (it + 1 < NIT_);
        // ---- issue next-iter A global loads (regs) + B glds (into nxt) ----
        if (pre) {
            if (ATRANS) {
                int m = t & 127, gh = (t >> 7) * 2;
                #pragma unroll
                for (int g2 = 0; g2 < 2; ++g2) {
                    int g = gh + g2;
                    #pragma unroll
                    for (int i = 0; i < 8; ++i)
                        ar16[g2 * 8 + i] = Ab[(size_t)(cb + g * 8 + i) * 1024 + m0 + m];
                }
            } else {
                #pragma unroll
                for (int p = 0; p < 4; ++p) {
                    int m = (t >> 3) + p * 32, c4 = (t & 7) * 4;
                    *(float4*)&ar16[p * 4] =
                        *(const float4*)&Ab[(size_t)(m0 + m) * 1024 + cb + c4];
                }
            }
            #pragma unroll
            for (int j = 0; j < 2; ++j) {
                int s = wave * 2 + j;
                int qq = s >> 1, nh = (s & 1) * 64;
                const unsigned short* gh = BbH + (size_t)(nh + lane) * 1024 + cb + qq * 8;
                const unsigned short* gl = BbL + (size_t)(nh + lane) * 1024 + cb + qq * 8;
                __builtin_amdgcn_global_load_lds((gu32*)gh, (lu32*)&sBh[nxt][qq * 1024 + nh * 8], 16, 0, 0);
                __builtin_amdgcn_global_load_lds((gu32*)gl, (lu32*)&sBl[nxt][qq * 1024 + nh * 8], 16, 0, 0);
            }
        }
        // ---- fragments + 48 MFMA on cur ----
        bf16x8 ah[4], al[4], bh[4], bl[4];
        #pragma unroll
        for (int mt = 0; mt < 4; ++mt) {
            int off = (wm + mt * 16 + fr) * 40 + q * 8;
            ah[mt] = *(const bf16x8*)&sAh[cur][off];
            al[mt] = *(const bf16x8*)&sAl[cur][off];
        }
        #pragma unroll
        for (int nt = 0; nt < 4; ++nt) {
            int off = q * 1024 + (wn + nt * 16 + fr) * 8;
            bh[nt] = *(const bf16x8*)&sBh[cur][off];
            bl[nt] = *(const bf16x8*)&sBl[cur][off];
        }
        #pragma unroll
        for (int mt = 0; mt < 4; ++mt)
            #pragma unroll
            for (int nt = 0; nt < 4; ++nt) {
                acc[mt][nt] = __builtin_amdgcn_mfma_f32_16x16x32_bf16(
                    ah[mt], bh[nt], acc[mt][nt], 0, 0, 0);
                acc[mt][nt] = __builtin_amdgcn_mfma_f32_16x16x32_bf16(
                    ah[mt], bl[nt], acc[mt][nt], 0, 0, 0);
                acc[mt][nt] = __builtin_amdgcn_mfma_f32_16x16x32_bf16(
                    al[mt], bh[nt], acc[mt][nt], 0, 0, 0);
            }
        // ---- convert + write next A into nxt ----
        if (pre) {
            if (ATRANS) {
                int m = t & 127, gh = (t >> 7) * 2;
                #pragma unroll
                for (int g2 = 0; g2 < 2; ++g2) {
                    int g = gh + g2;
                    bf16x8 hv, lv;
                    #pragma unroll
                    for (int i = 0; i < 8; ++i) {
                        unsigned short h = f2bf(ar16[g2 * 8 + i]);
                        hv[i] = (short)h;
                        lv[i] = (short)f2bf(ar16[g2 * 8 + i] - bf2f(h));
                    }
                    *(bf16x8*)&sAh[nxt][m * 40 + g * 8] = hv;
                    *(bf16x8*)&sAl[nxt][m * 40 + g * 8] = lv;
                }
            } else {
                #pragma unroll
                for (int p = 0; p < 4; ++p) {
                    int m = (t >> 3) + p * 32, c4 = (t & 7) * 4;
                    unsigned short hs[4], ls[4];
                    #pragma unroll
                    for (int i = 0; i < 4; ++i) {
                        float v = ar16[p * 4 + i];
                        hs[i] = f2bf(v);
                        ls[i] = f2bf(v - bf2f(hs[i]));
                    }
                    int off = m * 40 + c4;
                    *(uint2*)&sAh[nxt][off] = (uint2){(unsigned)hs[0] | ((unsigned)hs[1] << 16),
                                                      (unsigned)hs[2] | ((unsigned)hs[3] << 16)};
                    *(uint2*)&sAl[nxt][off] = (uint2){(unsigned)ls[0] | ((unsigned)ls[1] << 16),
                                                      (unsigned)ls[2] | ((unsigned)ls[3] << 16)};
                }
            }
        }
        __syncthreads();
    }
    // ---- store partials: P[ks][b][m][n] ----
    float* Pb = P + ((size_t)(ks * B_ + b) * 1024 + m0) * 128;
    #pragma unroll
    for (int mt = 0; mt < 4; ++mt)
        #pragma unroll
        for (int nt = 0; nt < 4; ++nt) {
            int col = wn + nt * 16 + fr;
            #pragma unroll
            for (int r = 0; r < 4; ++r)
                Pb[(size_t)(wm + mt * 16 + q * 4 + r) * 128 + col] = acc[mt][nt][r];
        }
}

// ---------------------------------------------------------------------------
// Reduce GEMM1 partials + complex-ratio weight + transpose -> G^T hi/lo [d][k]
// Block: 16 k x 128 d. Grid = 64 ktiles * B_ = 512.
// ---------------------------------------------------------------------------
__global__ __launch_bounds__(256) void k_gepi(
    const float* __restrict__ P, const float* __restrict__ EigVals,
    const float* __restrict__ par,
    unsigned short* __restrict__ GTh, unsigned short* __restrict__ GTl) {
    __shared__ float parS[3 * DS_];
    __shared__ float Gs[16][132];
    int t = threadIdx.x;
    for (int i = t; i < 3 * DS_; i += 256) parS[i] = par[i];
    __syncthreads();
    int bx = blockIdx.x;
    int kt = bx & 63, b = bx >> 6;
    int k0 = kt * 16;
    #pragma unroll
    for (int sub = 0; sub < 2; ++sub) {
        int k = (t >> 5) + sub * 8;
        int d4 = (t & 31) * 4;
        int row = b * 1024 + k0 + k;
        float4 s = {0.f, 0.f, 0.f, 0.f};
        #pragma unroll
        for (int sl = 0; sl < KS_; ++sl) {
            float4 v = *(const float4*)&P[((size_t)sl * 8192 + row) * 128 + d4];
            s.x += v.x; s.y += v.y; s.z += v.z; s.w += v.w;
        }
        float ev = 1.0f - EigVals[row];
        float qv[4] = {s.x, s.y, s.z, s.w};
        float o[4];
        #pragma unroll
        for (int c = 0; c < 4; ++c) {
            int dd = d4 + c;
            float w = 0.f;
            #pragma unroll
            for (int ss = 0; ss < S_; ++ss) {
                float arp = parS[ss * D_ + dd];
                float aip = parS[DS_ + ss * D_ + dd];
                float cc  = parS[2 * DS_ + ss * D_ + dd];
                float a = ev * arp, bi = ev * aip;
                float oma = 1.0f - a;            // exact (Sterbenz), a in [0.5,1]
                float b2 = bi * bi;
                float num = fmaf(a, oma, -b2);
                float den = fmaf(oma, oma, b2);  // no cancellation
                float r = __builtin_amdgcn_rcpf(den);
                r = r * (2.0f - den * r);
                w = fmaf(cc, num * r, w);
            }
            o[c] = qv[c] * w;
        }
        *(float4*)&Gs[k][d4] = (float4){o[0], o[1], o[2], o[3]};
    }
    __syncthreads();
    int d = t >> 1, kc = (t & 1) * 8;
    bf16x8 hv, lv;
    #pragma unroll
    for (int i = 0; i < 8; ++i) {
        float v = Gs[kc + i][d];
        unsigned short h = f2bf(v);
        hv[i] = (short)h;
        lv[i] = (short)f2bf(v - bf2f(h));
    }
    size_t off = ((size_t)b * 128 + d) * 1024 + k0 + kc;
    *(bf16x8*)&GTh[off] = hv;
    *(bf16x8*)&GTl[off] = lv;
}

// ---------------------------------------------------------------------------
// Reduce GEMM2 partials, *rn, silu, out-proj -> y. 16 rows/block, 512 blocks.
// ---------------------------------------------------------------------------
__global__ __launch_bounds__(256) void k_out(
    const float* __restrict__ P, const float* __restrict__ rn,
    const float* __restrict__ W_out, const float* __restrict__ b_out,
    float* __restrict__ y) {
    __shared__ float Ys[16][128];
    int row0 = blockIdx.x * 16;              // global row = b*L + l
    int t = threadIdx.x;
    #pragma unroll
    for (int r = 0; r < 2; ++r) {
        int idx = t + r * 256;
        int rr = idx >> 5, d4 = (idx & 31) * 4;
        int grow = row0 + rr;
        float4 s = {0.f, 0.f, 0.f, 0.f};
        #pragma unroll
        for (int sl = 0; sl < KS_; ++sl) {
            float4 v = *(const float4*)&P[((size_t)sl * 8192 + grow) * 128 + d4];
            s.x += v.x; s.y += v.y; s.z += v.z; s.w += v.w;
        }
        float rv = rn[grow];
        float o[4] = {s.x * rv, s.y * rv, s.z * rv, s.w * rv};
        #pragma unroll
        for (int c = 0; c < 4; ++c) {
            float sig = 1.0f / (1.0f + __expf(-o[c]));
            Ys[rr][d4 + c] = o[c] * sig;
        }
    }
    __syncthreads();
    int j = t & 127, h = t >> 7;
    float a2[8];
    #pragma unroll
    for (int r = 0; r < 8; ++r) a2[r] = 0.f;
    for (int dd = 0; dd < 128; dd += 4) {
        float w0 = W_out[(dd + 0) * 128 + j];
        float w1 = W_out[(dd + 1) * 128 + j];
        float w2 = W_out[(dd + 2) * 128 + j];
        float w3 = W_out[(dd + 3) * 128 + j];
        #pragma unroll
        for (int r = 0; r < 8; ++r) {
            float4 yv = *(float4*)&Ys[h * 8 + r][dd];
            a2[r] = fmaf(yv.x, w0, a2[r]);
            a2[r] = fmaf(yv.y, w1, a2[r]);
            a2[r] = fmaf(yv.z, w2, a2[r]);
            a2[r] = fmaf(yv.w, w3, a2[r]);
        }
    }
    float bo = b_out[j];
    #pragma unroll
    for (int r = 0; r < 8; ++r)
        y[(size_t)(row0 + h * 8 + r) * D_ + j] = a2[r] + bo;
}

// ---------------------------------------------------------------------------
extern "C" void kernel_launch(void* const* d_in, const int* in_sizes, int n_in,
                              void* d_out, int out_size, void* d_ws, size_t ws_size,
                              hipStream_t stream) {
    const float* x          = (const float*)d_in[0];
    const float* EigVecs    = (const float*)d_in[2];
    const float* EigVals    = (const float*)d_in[3];
    const float* bn_gamma   = (const float*)d_in[4];
    const float* bn_beta    = (const float*)d_in[5];
    const float* bn_mean    = (const float*)d_in[6];
    const float* bn_var     = (const float*)d_in[7];
    const float* W_in       = (const float*)d_in[8];
    const float* b_in       = (const float*)d_in[9];
    const float* log_Delta  = (const float*)d_in[10];
    const float* Bp         = (const float*)d_in[11];
    const float* Cp         = (const float*)d_in[12];
    const float* log_A_real = (const float*)d_in[13];
    const float* A_imag     = (const float*)d_in[14];
    const float* W_out      = (const float*)d_in[15];
    const float* b_out      = (const float*)d_in[16];

    float* y = (float*)d_out;
    char* w = (char*)d_ws;
    // byte layout (total ~25.2 MB)
    float* rn            = (float*)(w);                       // 32 KB
    float* par           = (float*)(w + 32768);               // 24 KB
    unsigned short* uTh  = (unsigned short*)(w + 65536);      // 2 MB
    unsigned short* uTl  = (unsigned short*)(w + 65536 + (1u << 21));
    unsigned short* GTh  = (unsigned short*)(w + 65536 + 2 * (1u << 21));
    unsigned short* GTl  = (unsigned short*)(w + 65536 + 3 * (1u << 21));
    float* P             = (float*)(w + 65536 + 4 * (1u << 21));  // KS_*4 MB

    k_params<<<dim3(8), dim3(256), 0, stream>>>(log_Delta, Bp, Cp, log_A_real, A_imag, par);
    k_rownorm<<<dim3(B_ * L_), dim3(256), 0, stream>>>(EigVecs, rn);
    k_inproj<<<dim3(B_ * L_ / 16), dim3(256), 0, stream>>>(
        x, bn_gamma, bn_beta, bn_mean, bn_var, W_in, b_in, rn, uTh, uTl);
    // GEMM1: QTX[k][d] partials; A = E^T (ATRANS), B = u^T
    k_gemm<true><<<dim3(B_ * 8 * KS_), dim3(256), 0, stream>>>(EigVecs, uTh, uTl, P);
    k_gepi<<<dim3(B_ * 64), dim3(256), 0, stream>>>(P, EigVals, par, GTh, GTl);
    // GEMM2: yssm[l][d] partials; A = E (natural), B = G^T
    k_gemm<false><<<dim3(B_ * 8 * KS_), dim3(256), 0, stream>>>(EigVecs, GTh, GTl, P);
    k_out<<<dim3(B_ * L_ / 16), dim3(256), 0, stream>>>(P, rn, W_out, b_out, y);
}

// Round 5
// 179.388 us; speedup vs baseline: 1.2784x; 1.0305x over previous
//
#include <hip/hip_runtime.h>
#include <math.h>

#define B_ 8
#define L_ 1024
#define K_ 1024
#define D_ 128
#define S_ 16
#define DS_ (D_ * S_)
#define KS_ 4            // split-K slices per GEMM
#define CSL_ 256         // contraction slice = 1024/KS_
#define NIT_ 8           // CSL_/32

typedef short bf16x8 __attribute__((ext_vector_type(8)));
typedef float f32x4 __attribute__((ext_vector_type(4)));
typedef __attribute__((address_space(1))) const unsigned int gu32;
typedef __attribute__((address_space(3))) unsigned int lu32;

__device__ inline unsigned short f2bf(float f) {
    unsigned int u = __float_as_uint(f);
    u = (u + 0x7fffu + ((u >> 16) & 1u)) >> 16;   // RNE
    return (unsigned short)u;
}
__device__ inline float bf2f(unsigned short h) {
    return __uint_as_float(((unsigned int)h) << 16);
}

// B operands (u^T, G^T) are stored PRE-SWIZZLED in the exact order the GEMM's
// global_load_lds consumes: idx = ((((b*32 + ct)*4 + q)*128 + n)*8 + i)
// where c (contraction) = ct*32 + q*8 + i, n = output column (d).
__device__ inline size_t bswz(int b, int c, int n) {
    return ((((size_t)b * 32 + (c >> 5)) * 4 + ((c >> 3) & 3)) * 128 + n) * 8;
}

// ---------------------------------------------------------------------------
// Params in double: ar/ai = Re/Im(Abar[d,s]), c = delta*Bp*Cp. Layout [s][d].
// ---------------------------------------------------------------------------
__global__ void k_params(const float* __restrict__ log_Delta,
                         const float* __restrict__ Bp,
                         const float* __restrict__ Cp,
                         const float* __restrict__ log_A_real,
                         const float* __restrict__ A_imag,
                         float* __restrict__ par) {
    int i = blockIdx.x * blockDim.x + threadIdx.x;   // i = d*S + s
    if (i >= DS_) return;
    int d = i >> 4;
    int s = i & 15;
    double delta = exp((double)log_Delta[d]);
    double Are = -exp((double)log_A_real[i]);
    double Aim = (double)A_imag[i];
    double mag = exp(-1e-3 + delta * Are);
    double ang = delta * Aim;
    int o = s * D_ + d;
    par[o]            = (float)(mag * cos(ang));
    par[DS_ + o]      = (float)(mag * sin(ang));
    par[2 * DS_ + o]  = (float)(delta * (double)Bp[i] * (double)Cp[i]);
}

// ---------------------------------------------------------------------------
__global__ __launch_bounds__(256) void k_rownorm(const float* __restrict__ E,
                                                 float* __restrict__ rn) {
    int row = blockIdx.x;
    const float4* p = (const float4*)(E + (size_t)row * K_);
    int t = threadIdx.x;
    float4 v = p[t];
    float s = v.x * v.x + v.y * v.y + v.z * v.z + v.w * v.w;
    #pragma unroll
    for (int off = 32; off > 0; off >>= 1) s += __shfl_down(s, off, 64);
    __shared__ float red[4];
    if ((t & 63) == 0) red[t >> 6] = s;
    __syncthreads();
    if (t == 0) rn[row] = 1.0f / sqrtf(red[0] + red[1] + red[2] + red[3]);
}

// ---------------------------------------------------------------------------
// In-proj: u' = rn * x1 * silu(z), stored swizzled bf16 hi/lo (see bswz).
// ---------------------------------------------------------------------------
__global__ __launch_bounds__(256) void k_inproj(
    const float* __restrict__ x, const float* __restrict__ g,
    const float* __restrict__ beta, const float* __restrict__ mean,
    const float* __restrict__ var, const float* __restrict__ W_in,
    const float* __restrict__ b_in, const float* __restrict__ rn,
    unsigned short* __restrict__ uswH, unsigned short* __restrict__ uswL) {
    __shared__ float xb[16][128];
    int row0 = blockIdx.x * 16;
    int t = threadIdx.x;
    #pragma unroll
    for (int p = 0; p < 8; ++p) {
        int idx = t + p * 256;
        int dd = idx & 127, r = idx >> 7;
        float sc = g[dd] / sqrtf(var[dd] + 1e-5f);
        xb[r][dd] = (x[(size_t)(row0 + r) * D_ + dd] - mean[dd]) * sc + beta[dd];
    }
    __syncthreads();
    int j = t & 127, half = t >> 7;
    float acc1[8], acc2[8];
    #pragma unroll
    for (int r = 0; r < 8; ++r) { acc1[r] = 0.f; acc2[r] = 0.f; }
    #pragma unroll 4
    for (int dd = 0; dd < 128; ++dd) {
        float w1 = W_in[dd * 256 + j];
        float w2 = W_in[dd * 256 + 128 + j];
        #pragma unroll
        for (int r = 0; r < 8; ++r) {
            float xv = xb[half * 8 + r][dd];
            acc1[r] = fmaf(xv, w1, acc1[r]);
            acc2[r] = fmaf(xv, w2, acc2[r]);
        }
    }
    float b1 = b_in[j], b2 = b_in[128 + j];
    bf16x8 hv, lv;
    #pragma unroll
    for (int r = 0; r < 8; ++r) {
        int row = row0 + half * 8 + r;
        float x1 = acc1[r] + b1;
        float z  = acc2[r] + b2;
        float sig = 1.0f / (1.0f + __expf(-z));
        float uv = rn[row] * x1 * z * sig;
        unsigned short h = f2bf(uv);
        hv[r] = (short)h;
        lv[r] = (short)f2bf(uv - bf2f(h));
    }
    int b = row0 >> 10;
    int l0 = (row0 & 1023) + half * 8;       // multiple of 8
    size_t off = bswz(b, l0, j);
    *(bf16x8*)&uswH[off] = hv;
    *(bf16x8*)&uswL[off] = lv;
}

// ---------------------------------------------------------------------------
// MFMA GEMM, split bf16 hi/lo (3 products), split-K partials.
// C[b][m][n] = sum_c A[m][c]*B[c][n]; M=1024, N=128, contraction 1024.
//   ATRANS=1: A[m][c] = E[b][c][m]  (GEMM1: m=k, c=l)
//   ATRANS=0: A[m][c] = E[b][m][c]  (GEMM2: m=l, c=k)
// B pre-swizzled hi/lo (bswz layout). Tile 64m x 128n, BK=32, slice 256.
// Grid = 16mt * KS_ * B_ = 512 -> 2 blocks/CU. Single-buffer LDS ~27 KB.
// 4 waves, each 64m x 32n (4x2 mfma tiles, 3 products = 24 MFMA/iter).
// LDS A: row stride 40 shorts, c-group rotated by (m>>3) -> <=2-way banks.
// LDS B: q-stride 1032 shorts -> conflict-free frag reads.
// ---------------------------------------------------------------------------
template<bool ATRANS>
__global__ __launch_bounds__(256, 2) void k_gemm(
    const float* __restrict__ Asrc,
    const unsigned short* __restrict__ BsrcH,
    const unsigned short* __restrict__ BsrcL,
    float* __restrict__ P) {
    __shared__ unsigned short sAh[64 * 40];
    __shared__ unsigned short sAl[64 * 40];
    __shared__ unsigned short sBh[4224];
    __shared__ unsigned short sBl[4224];
    int bx = blockIdx.x;
    int ks = bx & (KS_ - 1);
    int mt16 = (bx >> 2) & 15;
    int b = bx >> 6;
    int m0 = mt16 * 64;
    int cbase = ks * CSL_;
    const float* Ab = Asrc + (size_t)b * 1024 * 1024;
    int t = threadIdx.x;
    int wave = t >> 6, lane = t & 63;
    int fr = lane & 15, q = lane >> 4;
    int wn = wave * 32;
    f32x4 acc[4][2];
    #pragma unroll
    for (int i = 0; i < 4; ++i)
        #pragma unroll
        for (int j = 0; j < 2; ++j) acc[i][j] = (f32x4){0.f, 0.f, 0.f, 0.f};

    for (int it = 0; it < NIT_; ++it) {
        int cb = cbase + it * 32;
        // ---- stage A (global fp32 -> hi/lo bf16 -> LDS) ----
        if (ATRANS) {
            int m = t & 63, cg = t >> 6;           // c-group cg: c = cb+cg*8+i
            float v[8];
            #pragma unroll
            for (int i = 0; i < 8; ++i)
                v[i] = Ab[(size_t)(cb + cg * 8 + i) * 1024 + m0 + m];
            bf16x8 hv, lv;
            #pragma unroll
            for (int i = 0; i < 8; ++i) {
                unsigned short h = f2bf(v[i]);
                hv[i] = (short)h;
                lv[i] = (short)f2bf(v[i] - bf2f(h));
            }
            int p = (cg + (m >> 3)) & 3;
            *(bf16x8*)&sAh[m * 40 + p * 8] = hv;
            *(bf16x8*)&sAl[m * 40 + p * 8] = lv;
        } else {
            int m = t >> 2, cg = t & 3;
            float4 v0 = *(const float4*)&Ab[(size_t)(m0 + m) * 1024 + cb + cg * 8];
            float4 v1 = *(const float4*)&Ab[(size_t)(m0 + m) * 1024 + cb + cg * 8 + 4];
            float v[8] = {v0.x, v0.y, v0.z, v0.w, v1.x, v1.y, v1.z, v1.w};
            bf16x8 hv, lv;
            #pragma unroll
            for (int i = 0; i < 8; ++i) {
                unsigned short h = f2bf(v[i]);
                hv[i] = (short)h;
                lv[i] = (short)f2bf(v[i] - bf2f(h));
            }
            int p = (cg + (m >> 3)) & 3;
            *(bf16x8*)&sAh[m * 40 + p * 8] = hv;
            *(bf16x8*)&sAl[m * 40 + p * 8] = lv;
        }
        // ---- stage B via coalesced global_load_lds (4 per wave) ----
        {
            int ct = (cbase >> 5) + it;
            size_t src0 = (((size_t)(b * 32 + ct)) * 4) * 1024;  // *4q*128n*8i
            #pragma unroll
            for (int j = 0; j < 4; ++j) {
                int s = wave + j * 4;
                int qq = s & 3, nh = (s >> 2) & 1, hl = s >> 3;
                const unsigned short* src =
                    (hl ? BsrcL : BsrcH) + src0 + ((size_t)qq * 128 + nh * 64 + lane) * 8;
                unsigned short* dst =
                    (hl ? sBl : sBh) + qq * 1032 + nh * 512;
                __builtin_amdgcn_global_load_lds((gu32*)src, (lu32*)dst, 16, 0, 0);
            }
        }
        __syncthreads();
        // ---- fragments + 24 MFMA ----
        bf16x8 ah[4], al[4], bh[2], bl[2];
        #pragma unroll
        for (int mt = 0; mt < 4; ++mt) {
            int r = mt * 16 + fr;
            int p = (q + (r >> 3)) & 3;
            int off = r * 40 + p * 8;
            ah[mt] = *(const bf16x8*)&sAh[off];
            al[mt] = *(const bf16x8*)&sAl[off];
        }
        #pragma unroll
        for (int nt = 0; nt < 2; ++nt) {
            int off = q * 1032 + (wn + nt * 16 + fr) * 8;
            bh[nt] = *(const bf16x8*)&sBh[off];
            bl[nt] = *(const bf16x8*)&sBl[off];
        }
        #pragma unroll
        for (int mt = 0; mt < 4; ++mt)
            #pragma unroll
            for (int nt = 0; nt < 2; ++nt) {
                acc[mt][nt] = __builtin_amdgcn_mfma_f32_16x16x32_bf16(
                    ah[mt], bh[nt], acc[mt][nt], 0, 0, 0);
                acc[mt][nt] = __builtin_amdgcn_mfma_f32_16x16x32_bf16(
                    ah[mt], bl[nt], acc[mt][nt], 0, 0, 0);
                acc[mt][nt] = __builtin_amdgcn_mfma_f32_16x16x32_bf16(
                    al[mt], bh[nt], acc[mt][nt], 0, 0, 0);
            }
        __syncthreads();
    }
    // ---- store partials: P[ks][b][m][n] ----
    float* Pb = P + ((size_t)(ks * B_ + b) * 1024 + m0) * 128;
    #pragma unroll
    for (int mt = 0; mt < 4; ++mt)
        #pragma unroll
        for (int nt = 0; nt < 2; ++nt) {
            int col = wn + nt * 16 + fr;
            #pragma unroll
            for (int r = 0; r < 4; ++r)
                Pb[(size_t)(mt * 16 + q * 4 + r) * 128 + col] = acc[mt][nt][r];
        }
}

// ---------------------------------------------------------------------------
// Reduce GEMM1 partials + complex-ratio weight -> G, stored swizzled hi/lo.
// Block: 16 k x 128 d. Grid = 64 ktiles * B_ = 512.
// ---------------------------------------------------------------------------
__global__ __launch_bounds__(256) void k_gepi(
    const float* __restrict__ P, const float* __restrict__ EigVals,
    const float* __restrict__ par,
    unsigned short* __restrict__ GswH, unsigned short* __restrict__ GswL) {
    __shared__ float parS[3 * DS_];
    __shared__ float Gs[16][132];
    int t = threadIdx.x;
    for (int i = t; i < 3 * DS_; i += 256) parS[i] = par[i];
    __syncthreads();
    int bx = blockIdx.x;
    int kt = bx & 63, b = bx >> 6;
    int k0 = kt * 16;
    #pragma unroll
    for (int sub = 0; sub < 2; ++sub) {
        int k = (t >> 5) + sub * 8;
        int d4 = (t & 31) * 4;
        int row = b * 1024 + k0 + k;
        float4 s = {0.f, 0.f, 0.f, 0.f};
        #pragma unroll
        for (int sl = 0; sl < KS_; ++sl) {
            float4 v = *(const float4*)&P[((size_t)sl * 8192 + row) * 128 + d4];
            s.x += v.x; s.y += v.y; s.z += v.z; s.w += v.w;
        }
        float ev = 1.0f - EigVals[row];
        float qv[4] = {s.x, s.y, s.z, s.w};
        float o[4];
        #pragma unroll
        for (int c = 0; c < 4; ++c) {
            int dd = d4 + c;
            float w = 0.f;
            #pragma unroll
            for (int ss = 0; ss < S_; ++ss) {
                float arp = parS[ss * D_ + dd];
                float aip = parS[DS_ + ss * D_ + dd];
                float cc  = parS[2 * DS_ + ss * D_ + dd];
                float a = ev * arp, bi = ev * aip;
                float oma = 1.0f - a;            // exact (Sterbenz), a in [0.5,1]
                float b2 = bi * bi;
                float num = fmaf(a, oma, -b2);
                float den = fmaf(oma, oma, b2);  // no cancellation
                float r = __builtin_amdgcn_rcpf(den);
                r = r * (2.0f - den * r);
                w = fmaf(cc, num * r, w);
            }
            o[c] = qv[c] * w;
        }
        *(float4*)&Gs[k][d4] = (float4){o[0], o[1], o[2], o[3]};
    }
    __syncthreads();
    int d = t >> 1, kc = (t & 1) * 8;
    bf16x8 hv, lv;
    #pragma unroll
    for (int i = 0; i < 8; ++i) {
        float v = Gs[kc + i][d];
        unsigned short h = f2bf(v);
        hv[i] = (short)h;
        lv[i] = (short)f2bf(v - bf2f(h));
    }
    size_t off = bswz(b, k0 + kc, d);
    *(bf16x8*)&GswH[off] = hv;
    *(bf16x8*)&GswL[off] = lv;
}

// ---------------------------------------------------------------------------
// Reduce GEMM2 partials, *rn, silu, out-proj -> y. 16 rows/block, 512 blocks.
// ---------------------------------------------------------------------------
__global__ __launch_bounds__(256) void k_out(
    const float* __restrict__ P, const float* __restrict__ rn,
    const float* __restrict__ W_out, const float* __restrict__ b_out,
    float* __restrict__ y) {
    __shared__ float Ys[16][128];
    int row0 = blockIdx.x * 16;              // global row = b*L + l
    int t = threadIdx.x;
    #pragma unroll
    for (int r = 0; r < 2; ++r) {
        int idx = t + r * 256;
        int rr = idx >> 5, d4 = (idx & 31) * 4;
        int grow = row0 + rr;
        float4 s = {0.f, 0.f, 0.f, 0.f};
        #pragma unroll
        for (int sl = 0; sl < KS_; ++sl) {
            float4 v = *(const float4*)&P[((size_t)sl * 8192 + grow) * 128 + d4];
            s.x += v.x; s.y += v.y; s.z += v.z; s.w += v.w;
        }
        float rv = rn[grow];
        float o[4] = {s.x * rv, s.y * rv, s.z * rv, s.w * rv};
        #pragma unroll
        for (int c = 0; c < 4; ++c) {
            float sig = 1.0f / (1.0f + __expf(-o[c]));
            Ys[rr][d4 + c] = o[c] * sig;
        }
    }
    __syncthreads();
    int j = t & 127, h = t >> 7;
    float a2[8];
    #pragma unroll
    for (int r = 0; r < 8; ++r) a2[r] = 0.f;
    for (int dd = 0; dd < 128; dd += 4) {
        float w0 = W_out[(dd + 0) * 128 + j];
        float w1 = W_out[(dd + 1) * 128 + j];
        float w2 = W_out[(dd + 2) * 128 + j];
        float w3 = W_out[(dd + 3) * 128 + j];
        #pragma unroll
        for (int r = 0; r < 8; ++r) {
            float4 yv = *(float4*)&Ys[h * 8 + r][dd];
            a2[r] = fmaf(yv.x, w0, a2[r]);
            a2[r] = fmaf(yv.y, w1, a2[r]);
            a2[r] = fmaf(yv.z, w2, a2[r]);
            a2[r] = fmaf(yv.w, w3, a2[r]);
        }
    }
    float bo = b_out[j];
    #pragma unroll
    for (int r = 0; r < 8; ++r)
        y[(size_t)(row0 + h * 8 + r) * D_ + j] = a2[r] + bo;
}

// ---------------------------------------------------------------------------
extern "C" void kernel_launch(void* const* d_in, const int* in_sizes, int n_in,
                              void* d_out, int out_size, void* d_ws, size_t ws_size,
                              hipStream_t stream) {
    const float* x          = (const float*)d_in[0];
    const float* EigVecs    = (const float*)d_in[2];
    const float* EigVals    = (const float*)d_in[3];
    const float* bn_gamma   = (const float*)d_in[4];
    const float* bn_beta    = (const float*)d_in[5];
    const float* bn_mean    = (const float*)d_in[6];
    const float* bn_var     = (const float*)d_in[7];
    const float* W_in       = (const float*)d_in[8];
    const float* b_in       = (const float*)d_in[9];
    const float* log_Delta  = (const float*)d_in[10];
    const float* Bp         = (const float*)d_in[11];
    const float* Cp         = (const float*)d_in[12];
    const float* log_A_real = (const float*)d_in[13];
    const float* A_imag     = (const float*)d_in[14];
    const float* W_out      = (const float*)d_in[15];
    const float* b_out      = (const float*)d_in[16];

    float* y = (float*)d_out;
    char* w = (char*)d_ws;
    float* rn            = (float*)(w);                       // 32 KB
    float* par           = (float*)(w + 32768);               // 24 KB
    unsigned short* uswH = (unsigned short*)(w + 65536);      // 2 MB each
    unsigned short* uswL = (unsigned short*)(w + 65536 + (1u << 21));
    unsigned short* GswH = (unsigned short*)(w + 65536 + 2 * (1u << 21));
    unsigned short* GswL = (unsigned short*)(w + 65536 + 3 * (1u << 21));
    float* P             = (float*)(w + 65536 + 4 * (1u << 21));  // 16 MB

    k_params<<<dim3(8), dim3(256), 0, stream>>>(log_Delta, Bp, Cp, log_A_real, A_imag, par);
    k_rownorm<<<dim3(B_ * L_), dim3(256), 0, stream>>>(EigVecs, rn);
    k_inproj<<<dim3(B_ * L_ / 16), dim3(256), 0, stream>>>(
        x, bn_gamma, bn_beta, bn_mean, bn_var, W_in, b_in, rn, uswH, uswL);
    // GEMM1: QTX[k][d] partials; A = E^T, B = u' swizzled
    k_gemm<true><<<dim3(16 * KS_ * B_), dim3(256), 0, stream>>>(EigVecs, uswH, uswL, P);
    k_gepi<<<dim3(B_ * 64), dim3(256), 0, stream>>>(P, EigVals, par, GswH, GswL);
    // GEMM2: yssm[l][d] partials; A = E, B = G swizzled
    k_gemm<false><<<dim3(16 * KS_ * B_), dim3(256), 0, stream>>>(EigVecs, GswH, GswL, P);
    k_out<<<dim3(B_ * L_ / 16), dim3(256), 0, stream>>>(P, rn, W_out, b_out, y);
}

// Round 6
// 177.052 us; speedup vs baseline: 1.2953x; 1.0132x over previous
//
#include <hip/hip_runtime.h>
#include <math.h>

#define B_ 8
#define L_ 1024
#define K_ 1024
#define D_ 128
#define S_ 16
#define DS_ (D_ * S_)
#define KS_ 8            // split-K slices per GEMM
#define CSL_ 128         // contraction slice = 1024/KS_
#define NIT_ 4           // CSL_/32

typedef short bf16x8 __attribute__((ext_vector_type(8)));
typedef float f32x4 __attribute__((ext_vector_type(4)));
typedef __attribute__((address_space(1))) const unsigned int gu32;
typedef __attribute__((address_space(3))) unsigned int lu32;

__device__ inline unsigned short f2bf(float f) {
    unsigned int u = __float_as_uint(f);
    u = (u + 0x7fffu + ((u >> 16) & 1u)) >> 16;   // RNE
    return (unsigned short)u;
}
__device__ inline float bf2f(unsigned short h) {
    return __uint_as_float(((unsigned int)h) << 16);
}

// B operands (u^T, G^T) stored PRE-SWIZZLED in glds consumption order:
// idx = ((((b*32 + ct)*4 + q)*128 + n)*8 + i), c = ct*32 + q*8 + i.
__device__ inline size_t bswz(int b, int c, int n) {
    return ((((size_t)b * 32 + (c >> 5)) * 4 + ((c >> 3) & 3)) * 128 + n) * 8;
}

// ---------------------------------------------------------------------------
// Params in double: ar/ai = Re/Im(Abar[d,s]), c = delta*Bp*Cp. Layout [s][d].
// ---------------------------------------------------------------------------
__global__ void k_params(const float* __restrict__ log_Delta,
                         const float* __restrict__ Bp,
                         const float* __restrict__ Cp,
                         const float* __restrict__ log_A_real,
                         const float* __restrict__ A_imag,
                         float* __restrict__ par) {
    int i = blockIdx.x * blockDim.x + threadIdx.x;   // i = d*S + s
    if (i >= DS_) return;
    int d = i >> 4;
    int s = i & 15;
    double delta = exp((double)log_Delta[d]);
    double Are = -exp((double)log_A_real[i]);
    double Aim = (double)A_imag[i];
    double mag = exp(-1e-3 + delta * Are);
    double ang = delta * Aim;
    int o = s * D_ + d;
    par[o]            = (float)(mag * cos(ang));
    par[DS_ + o]      = (float)(mag * sin(ang));
    par[2 * DS_ + o]  = (float)(delta * (double)Bp[i] * (double)Cp[i]);
}

// ---------------------------------------------------------------------------
// Fused rownorm + in-proj: rn = 1/||E[row]||; u' = rn * x1 * silu(z),
// stored swizzled bf16 hi/lo. 16 rows/block, 512 blocks.
// ---------------------------------------------------------------------------
__global__ __launch_bounds__(256) void k_pre(
    const float* __restrict__ E, const float* __restrict__ x,
    const float* __restrict__ g, const float* __restrict__ beta,
    const float* __restrict__ mean, const float* __restrict__ var,
    const float* __restrict__ W_in, const float* __restrict__ b_in,
    float* __restrict__ rn_out,
    unsigned short* __restrict__ uswH, unsigned short* __restrict__ uswL) {
    __shared__ float xb[16][128];
    __shared__ float rsum[16];
    __shared__ float rnS[16];
    int row0 = blockIdx.x * 16;
    int t = threadIdx.x;
    // --- row norms: 16 threads per row ---
    {
        int r = t >> 4, tt = t & 15;
        const float4* Ep = (const float4*)(E + (size_t)(row0 + r) * K_);
        float s = 0.f;
        #pragma unroll
        for (int i = 0; i < 16; ++i) {
            float4 v = Ep[tt + i * 16];
            s += v.x * v.x + v.y * v.y + v.z * v.z + v.w * v.w;
        }
        s += __shfl_xor(s, 8, 64);
        s += __shfl_xor(s, 4, 64);
        s += __shfl_xor(s, 2, 64);
        s += __shfl_xor(s, 1, 64);
        if (tt == 0) rsum[r] = s;
    }
    // --- stage BN(x) ---
    #pragma unroll
    for (int p = 0; p < 8; ++p) {
        int idx = t + p * 256;
        int dd = idx & 127, r = idx >> 7;
        float sc = g[dd] / sqrtf(var[dd] + 1e-5f);
        xb[r][dd] = (x[(size_t)(row0 + r) * D_ + dd] - mean[dd]) * sc + beta[dd];
    }
    __syncthreads();
    if (t < 16) {
        float rv = 1.0f / sqrtf(rsum[t]);
        rnS[t] = rv;
        rn_out[row0 + t] = rv;
    }
    __syncthreads();
    int j = t & 127, half = t >> 7;
    float acc1[8], acc2[8];
    #pragma unroll
    for (int r = 0; r < 8; ++r) { acc1[r] = 0.f; acc2[r] = 0.f; }
    #pragma unroll 4
    for (int dd = 0; dd < 128; ++dd) {
        float w1 = W_in[dd * 256 + j];
        float w2 = W_in[dd * 256 + 128 + j];
        #pragma unroll
        for (int r = 0; r < 8; ++r) {
            float xv = xb[half * 8 + r][dd];
            acc1[r] = fmaf(xv, w1, acc1[r]);
            acc2[r] = fmaf(xv, w2, acc2[r]);
        }
    }
    float b1 = b_in[j], b2 = b_in[128 + j];
    bf16x8 hv, lv;
    #pragma unroll
    for (int r = 0; r < 8; ++r) {
        int rr = half * 8 + r;
        float x1 = acc1[r] + b1;
        float z  = acc2[r] + b2;
        float sig = 1.0f / (1.0f + __expf(-z));
        float uv = rnS[rr] * x1 * z * sig;
        unsigned short h = f2bf(uv);
        hv[r] = (short)h;
        lv[r] = (short)f2bf(uv - bf2f(h));
    }
    int b = row0 >> 10;
    int l0 = (row0 & 1023) + half * 8;
    size_t off = bswz(b, l0, j);
    *(bf16x8*)&uswH[off] = hv;
    *(bf16x8*)&uswL[off] = lv;
}

// ---------------------------------------------------------------------------
// MFMA GEMM, split bf16 hi/lo (3 products), split-K=8 partials.
// C[b][m][n] = sum_c A[m][c]*B[c][n]; M=1024, N=128.
//   ATRANS=1: A[m][c] = E[b][c][m]  (GEMM1: m=k, c=l)
//   ATRANS=0: A[m][c] = E[b][m][c]  (GEMM2: m=l, c=k)
// Tile 64m x 128n, BK=32, slice 128, NIT=4. Grid = KS_*16mt*B_ = 1024
// -> 4 blocks/CU (27 KB LDS, launch_bounds(256,4)). ks = bx&7 -> all blocks
// sharing a B-slice land on one XCD (L2 locality). A-loads software-pipelined
// into registers so their latency overlaps the MFMA section.
// ---------------------------------------------------------------------------
template<bool ATRANS>
__global__ __launch_bounds__(256, 4) void k_gemm(
    const float* __restrict__ Asrc,
    const unsigned short* __restrict__ BsrcH,
    const unsigned short* __restrict__ BsrcL,
    float* __restrict__ P) {
    __shared__ unsigned short sAh[64 * 40];
    __shared__ unsigned short sAl[64 * 40];
    __shared__ unsigned short sBh[4224];
    __shared__ unsigned short sBl[4224];
    int bx = blockIdx.x;
    int ks = bx & (KS_ - 1);
    int mt16 = (bx >> 3) & 15;
    int b = bx >> 7;
    int m0 = mt16 * 64;
    int cbase = ks * CSL_;
    const float* Ab = Asrc + (size_t)b * 1024 * 1024;
    int t = threadIdx.x;
    int wave = t >> 6, lane = t & 63;
    int fr = lane & 15, q = lane >> 4;
    int wn = wave * 32;
    int m_, cg_;
    if (ATRANS) { m_ = t & 63; cg_ = t >> 6; }
    else        { m_ = t >> 2; cg_ = t & 3; }
    f32x4 acc[4][2];
    #pragma unroll
    for (int i = 0; i < 4; ++i)
        #pragma unroll
        for (int j = 0; j < 2; ++j) acc[i][j] = (f32x4){0.f, 0.f, 0.f, 0.f};

    float v[8];
    // prologue: A regs for it=0
    if (ATRANS) {
        #pragma unroll
        for (int i = 0; i < 8; ++i)
            v[i] = Ab[(size_t)(cbase + cg_ * 8 + i) * 1024 + m0 + m_];
    } else {
        *(float4*)&v[0] = *(const float4*)&Ab[(size_t)(m0 + m_) * 1024 + cbase + cg_ * 8];
        *(float4*)&v[4] = *(const float4*)&Ab[(size_t)(m0 + m_) * 1024 + cbase + cg_ * 8 + 4];
    }

    #pragma unroll
    for (int it = 0; it < NIT_; ++it) {
        // ---- convert + ds_write current A ----
        {
            bf16x8 hv, lv;
            #pragma unroll
            for (int i = 0; i < 8; ++i) {
                unsigned short h = f2bf(v[i]);
                hv[i] = (short)h;
                lv[i] = (short)f2bf(v[i] - bf2f(h));
            }
            int p = (cg_ + (m_ >> 3)) & 3;
            *(bf16x8*)&sAh[m_ * 40 + p * 8] = hv;
            *(bf16x8*)&sAl[m_ * 40 + p * 8] = lv;
        }
        // ---- stage B via coalesced global_load_lds (4 per wave) ----
        {
            int ct = ks * 4 + it;
            size_t src0 = (((size_t)(b * 32 + ct)) * 4) * 1024;
            #pragma unroll
            for (int j = 0; j < 4; ++j) {
                int s = wave + j * 4;
                int qq = s & 3, nh = (s >> 2) & 1, hl = s >> 3;
                const unsigned short* src =
                    (hl ? BsrcL : BsrcH) + src0 + ((size_t)qq * 128 + nh * 64 + lane) * 8;
                unsigned short* dst =
                    (hl ? sBl : sBh) + qq * 1032 + nh * 512;
                __builtin_amdgcn_global_load_lds((gu32*)src, (lu32*)dst, 16, 0, 0);
            }
        }
        __syncthreads();
        // ---- prefetch next-iter A into regs (overlaps MFMA below) ----
        if (it + 1 < NIT_) {
            int cb = cbase + (it + 1) * 32;
            if (ATRANS) {
                #pragma unroll
                for (int i = 0; i < 8; ++i)
                    v[i] = Ab[(size_t)(cb + cg_ * 8 + i) * 1024 + m0 + m_];
            } else {
                *(float4*)&v[0] = *(const float4*)&Ab[(size_t)(m0 + m_) * 1024 + cb + cg_ * 8];
                *(float4*)&v[4] = *(const float4*)&Ab[(size_t)(m0 + m_) * 1024 + cb + cg_ * 8 + 4];
            }
        }
        // ---- fragments + 24 MFMA ----
        bf16x8 ah[4], al[4], bh[2], bl[2];
        #pragma unroll
        for (int mt = 0; mt < 4; ++mt) {
            int r = mt * 16 + fr;
            int p = (q + (r >> 3)) & 3;
            int off = r * 40 + p * 8;
            ah[mt] = *(const bf16x8*)&sAh[off];
            al[mt] = *(const bf16x8*)&sAl[off];
        }
        #pragma unroll
        for (int nt = 0; nt < 2; ++nt) {
            int off = q * 1032 + (wn + nt * 16 + fr) * 8;
            bh[nt] = *(const bf16x8*)&sBh[off];
            bl[nt] = *(const bf16x8*)&sBl[off];
        }
        #pragma unroll
        for (int mt = 0; mt < 4; ++mt)
            #pragma unroll
            for (int nt = 0; nt < 2; ++nt) {
                acc[mt][nt] = __builtin_amdgcn_mfma_f32_16x16x32_bf16(
                    ah[mt], bh[nt], acc[mt][nt], 0, 0, 0);
                acc[mt][nt] = __builtin_amdgcn_mfma_f32_16x16x32_bf16(
                    ah[mt], bl[nt], acc[mt][nt], 0, 0, 0);
                acc[mt][nt] = __builtin_amdgcn_mfma_f32_16x16x32_bf16(
                    al[mt], bh[nt], acc[mt][nt], 0, 0, 0);
            }
        __syncthreads();
    }
    // ---- store partials: P[ks][b][m][n] ----
    float* Pb = P + ((size_t)(ks * B_ + b) * 1024 + m0) * 128;
    #pragma unroll
    for (int mt = 0; mt < 4; ++mt)
        #pragma unroll
        for (int nt = 0; nt < 2; ++nt) {
            int col = wn + nt * 16 + fr;
            #pragma unroll
            for (int r = 0; r < 4; ++r)
                Pb[(size_t)(mt * 16 + q * 4 + r) * 128 + col] = acc[mt][nt][r];
        }
}

// ---------------------------------------------------------------------------
// Reduce GEMM1 partials + complex-ratio weight -> G, stored swizzled hi/lo.
// Block: 16 k x 128 d. Grid = 64 ktiles * B_ = 512.
// ---------------------------------------------------------------------------
__global__ __launch_bounds__(256) void k_gepi(
    const float* __restrict__ P, const float* __restrict__ EigVals,
    const float* __restrict__ par,
    unsigned short* __restrict__ GswH, unsigned short* __restrict__ GswL) {
    __shared__ float parS[3 * DS_];
    __shared__ float Gs[16][132];
    int t = threadIdx.x;
    for (int i = t; i < 3 * DS_; i += 256) parS[i] = par[i];
    __syncthreads();
    int bx = blockIdx.x;
    int kt = bx & 63, b = bx >> 6;
    int k0 = kt * 16;
    #pragma unroll
    for (int sub = 0; sub < 2; ++sub) {
        int k = (t >> 5) + sub * 8;
        int d4 = (t & 31) * 4;
        int row = b * 1024 + k0 + k;
        float4 s = {0.f, 0.f, 0.f, 0.f};
        #pragma unroll
        for (int sl = 0; sl < KS_; ++sl) {
            float4 v = *(const float4*)&P[((size_t)sl * 8192 + row) * 128 + d4];
            s.x += v.x; s.y += v.y; s.z += v.z; s.w += v.w;
        }
        float ev = 1.0f - EigVals[row];
        float qv[4] = {s.x, s.y, s.z, s.w};
        float o[4];
        #pragma unroll
        for (int c = 0; c < 4; ++c) {
            int dd = d4 + c;
            float w = 0.f;
            #pragma unroll
            for (int ss = 0; ss < S_; ++ss) {
                float arp = parS[ss * D_ + dd];
                float aip = parS[DS_ + ss * D_ + dd];
                float cc  = parS[2 * DS_ + ss * D_ + dd];
                float a = ev * arp, bi = ev * aip;
                float oma = 1.0f - a;            // exact (Sterbenz), a in [0.5,1]
                float b2 = bi * bi;
                float num = fmaf(a, oma, -b2);
                float den = fmaf(oma, oma, b2);  // no cancellation
                float r = __builtin_amdgcn_rcpf(den);
                r = r * (2.0f - den * r);
                w = fmaf(cc, num * r, w);
            }
            o[c] = qv[c] * w;
        }
        *(float4*)&Gs[k][d4] = (float4){o[0], o[1], o[2], o[3]};
    }
    __syncthreads();
    int d = t >> 1, kc = (t & 1) * 8;
    bf16x8 hv, lv;
    #pragma unroll
    for (int i = 0; i < 8; ++i) {
        float v = Gs[kc + i][d];
        unsigned short h = f2bf(v);
        hv[i] = (short)h;
        lv[i] = (short)f2bf(v - bf2f(h));
    }
    size_t off = bswz(b, k0 + kc, d);
    *(bf16x8*)&GswH[off] = hv;
    *(bf16x8*)&GswL[off] = lv;
}

// ---------------------------------------------------------------------------
// Reduce GEMM2 partials, *rn, silu, out-proj -> y. 16 rows/block, 512 blocks.
// ---------------------------------------------------------------------------
__global__ __launch_bounds__(256) void k_out(
    const float* __restrict__ P, const float* __restrict__ rn,
    const float* __restrict__ W_out, const float* __restrict__ b_out,
    float* __restrict__ y) {
    __shared__ float Ys[16][128];
    int row0 = blockIdx.x * 16;              // global row = b*L + l
    int t = threadIdx.x;
    #pragma unroll
    for (int r = 0; r < 2; ++r) {
        int idx = t + r * 256;
        int rr = idx >> 5, d4 = (idx & 31) * 4;
        int grow = row0 + rr;
        float4 s = {0.f, 0.f, 0.f, 0.f};
        #pragma unroll
        for (int sl = 0; sl < KS_; ++sl) {
            float4 v = *(const float4*)&P[((size_t)sl * 8192 + grow) * 128 + d4];
            s.x += v.x; s.y += v.y; s.z += v.z; s.w += v.w;
        }
        float rv = rn[grow];
        float o[4] = {s.x * rv, s.y * rv, s.z * rv, s.w * rv};
        #pragma unroll
        for (int c = 0; c < 4; ++c) {
            float sig = 1.0f / (1.0f + __expf(-o[c]));
            Ys[rr][d4 + c] = o[c] * sig;
        }
    }
    __syncthreads();
    int j = t & 127, h = t >> 7;
    float a2[8];
    #pragma unroll
    for (int r = 0; r < 8; ++r) a2[r] = 0.f;
    for (int dd = 0; dd < 128; dd += 4) {
        float w0 = W_out[(dd + 0) * 128 + j];
        float w1 = W_out[(dd + 1) * 128 + j];
        float w2 = W_out[(dd + 2) * 128 + j];
        float w3 = W_out[(dd + 3) * 128 + j];
        #pragma unroll
        for (int r = 0; r < 8; ++r) {
            float4 yv = *(float4*)&Ys[h * 8 + r][dd];
            a2[r] = fmaf(yv.x, w0, a2[r]);
            a2[r] = fmaf(yv.y, w1, a2[r]);
            a2[r] = fmaf(yv.z, w2, a2[r]);
            a2[r] = fmaf(yv.w, w3, a2[r]);
        }
    }
    float bo = b_out[j];
    #pragma unroll
    for (int r = 0; r < 8; ++r)
        y[(size_t)(row0 + h * 8 + r) * D_ + j] = a2[r] + bo;
}

// ---------------------------------------------------------------------------
extern "C" void kernel_launch(void* const* d_in, const int* in_sizes, int n_in,
                              void* d_out, int out_size, void* d_ws, size_t ws_size,
                              hipStream_t stream) {
    const float* x          = (const float*)d_in[0];
    const float* EigVecs    = (const float*)d_in[2];
    const float* EigVals    = (const float*)d_in[3];
    const float* bn_gamma   = (const float*)d_in[4];
    const float* bn_beta    = (const float*)d_in[5];
    const float* bn_mean    = (const float*)d_in[6];
    const float* bn_var     = (const float*)d_in[7];
    const float* W_in       = (const float*)d_in[8];
    const float* b_in       = (const float*)d_in[9];
    const float* log_Delta  = (const float*)d_in[10];
    const float* Bp         = (const float*)d_in[11];
    const float* Cp         = (const float*)d_in[12];
    const float* log_A_real = (const float*)d_in[13];
    const float* A_imag     = (const float*)d_in[14];
    const float* W_out      = (const float*)d_in[15];
    const float* b_out      = (const float*)d_in[16];

    float* y = (float*)d_out;
    char* w = (char*)d_ws;
    float* rn            = (float*)(w);                       // 32 KB
    float* par           = (float*)(w + 32768);               // 24 KB
    unsigned short* uswH = (unsigned short*)(w + 65536);      // 2 MB each
    unsigned short* uswL = (unsigned short*)(w + 65536 + (1u << 21));
    unsigned short* GswH = (unsigned short*)(w + 65536 + 2 * (1u << 21));
    unsigned short* GswL = (unsigned short*)(w + 65536 + 3 * (1u << 21));
    float* P             = (float*)(w + 65536 + 4 * (1u << 21));  // KS_*4 MB

    k_params<<<dim3(8), dim3(256), 0, stream>>>(log_Delta, Bp, Cp, log_A_real, A_imag, par);
    k_pre<<<dim3(B_ * L_ / 16), dim3(256), 0, stream>>>(
        EigVecs, x, bn_gamma, bn_beta, bn_mean, bn_var, W_in, b_in, rn, uswH, uswL);
    // GEMM1: QTX[k][d] partials; A = E^T, B = u' swizzled
    k_gemm<true><<<dim3(KS_ * 16 * B_), dim3(256), 0, stream>>>(EigVecs, uswH, uswL, P);
    k_gepi<<<dim3(B_ * 64), dim3(256), 0, stream>>>(P, EigVals, par, GswH, GswL);
    // GEMM2: yssm[l][d] partials; A = E, B = G swizzled
    k_gemm<false><<<dim3(KS_ * 16 * B_), dim3(256), 0, stream>>>(EigVecs, GswH, GswL, P);
    k_out<<<dim3(B_ * L_ / 16), dim3(256), 0, stream>>>(P, rn, W_out, b_out, y);
}